// Round 7
// baseline (109.269 us; speedup 1.0000x reference)
//
#include <hip/hip_runtime.h>
#include <hip/hip_bf16.h>
#include <stdint.h>

#define NVAR 32
#define LAGD 1024
#define BATCH 256
#define HDIM 512
#define SPLIT 16

typedef __attribute__((ext_vector_type(4))) float f32x4;
typedef __attribute__((ext_vector_type(8))) short short8;
typedef __attribute__((ext_vector_type(4))) unsigned short us4;
typedef __attribute__((ext_vector_type(8))) unsigned short us8;

__device__ __forceinline__ unsigned short f2bf(float f) {
  union { __hip_bfloat16 b; unsigned short s; } cv;
  cv.b = __float2bfloat16(f);
  return cv.s;
}
__device__ __forceinline__ us8 cvt8(f32x4 a, f32x4 b) {
  us8 u;
#pragma unroll
  for (int e = 0; e < 4; ++e) { u[e] = f2bf(a[e]); u[4 + e] = f2bf(b[e]); }
  return u;
}

// global -> LDS direct copy, 16 B per lane (dest = wave-uniform base + lane*16).
__device__ __forceinline__ void gload16(const void* g, const void* l) {
  __builtin_amdgcn_global_load_lds(
      (const __attribute__((address_space(1))) unsigned int*)(uintptr_t)g,
      (__attribute__((address_space(3))) unsigned int*)(unsigned int)(uintptr_t)l,
      16, 0, 0);
}

// Order-pinned global load.
__device__ __forceinline__ f32x4 gldx4(const float* p) {
  f32x4 r;
  asm volatile("global_load_dwordx4 %0, %1, off" : "=v"(r) : "v"(p) : "memory");
  return r;
}

#define WAITVM0() do { \
    asm volatile("s_waitcnt vmcnt(0)" ::: "memory"); \
    __builtin_amdgcn_sched_barrier(0); } while (0)

__device__ __forceinline__ void sync_ds() {
  asm volatile("s_waitcnt lgkmcnt(0)" ::: "memory");
  __builtin_amdgcn_s_barrier();
}

// ---------------------------------------------------------------------------
// K1: gates GEMM + LSTM activation, page-burst W streaming.
//   Block (v, h-tile 32), grid 512, 1 block/CU, 8 waves.
//   W read in supergroups of 4 k-tiles: 1 KB contiguous per row per thread
//   (full HBM page per activate) -> regs -> cvt -> LDS region (dbuf).
//   A (X, L2-resident): reg-staged fp32->bf16, LDS dbuf, depth-1.
//   vmcnt(0) per iteration (iterations are BW-paced; everything >=1 iter old
//   has landed -> no FIFO counting needed).
// ---------------------------------------------------------------------------
__global__ __launch_bounds__(512, 2) void k1_gates(
    const float* __restrict__ X,          // [256][32][1024]
    const float* __restrict__ W,          // [32][2048][1024]
    const float* __restrict__ b_ih,
    const float* __restrict__ b_hh,
    const float* __restrict__ imp,
    unsigned short* __restrict__ aggT)    // [32 v][8 kt][256][64] swizzled bf16
{
  const int bid = blockIdx.x;
  const int chunk = ((bid & 7) << 6) | (bid >> 3);   // XCD-contiguous
  const int v = chunk >> 4;
  const int h0 = (chunk & 15) << 5;

  const int t = threadIdx.x, lane = t & 63, wave = t >> 6;
  const int wm = wave & 3, wh = wave >> 2;

  __shared__ __align__(16) unsigned char smem[131072]; // A:2x32K @0, B:2x32K @65536

  // A staging: thread owns rows rt+64p (p=0..3), 8 fp32 cols at c8
  const int rt = t >> 3, c8 = (t & 7) << 3;
  const float* Asrc = X + (size_t)rt * (NVAR * LAGD) + (size_t)v * LAGD + c8;
  const unsigned awoff = (unsigned)(((rt << 7) + (c8 << 1)) ^ ((rt & 7) << 4));

  // B group staging: 64 rows (32 i + 32 g); thread reads 128 B contiguous
  // (32 floats) of its row per supergroup: floats [(t&7)*32, +32) of 256.
  const int brow = t >> 3;
  const int wrow = (brow < 32) ? (h0 + brow) : (1024 + h0 + brow - 32);
  const float* Bsrc = W + (size_t)v * (2048 * LAGD) + (size_t)wrow * LAGD + ((t & 7) << 5);
  const unsigned btile = (unsigned)((t & 7) >> 1);        // k-tile within group
  const unsigned bkb   = (unsigned)(((t & 7) & 1) << 6);  // byte base within tile row

  f32x4 acc_i[4] = {}, acc_g[4] = {};
  f32x4 pa[4][2], pb[8];

#define ALOAD(KT) do { \
    _Pragma("unroll") for (int _p = 0; _p < 4; ++_p) { \
      pa[_p][0] = gldx4(Asrc + (size_t)_p * 64 * (NVAR * LAGD) + (KT) * 64); \
      pa[_p][1] = gldx4(Asrc + (size_t)_p * 64 * (NVAR * LAGD) + (KT) * 64 + 4); \
    } } while (0)

#define ASTORE(BUF) do { \
    _Pragma("unroll") for (int _p = 0; _p < 4; ++_p) \
      *(us8*)(smem + (BUF) * 32768u + awoff + _p * 8192u) = cvt8(pa[_p][0], pa[_p][1]); \
  } while (0)

#define BGLOAD(G) do { \
    _Pragma("unroll") for (int _e = 0; _e < 8; ++_e) \
      pb[_e] = gldx4(Bsrc + (size_t)(G) * 256 + _e * 4); } while (0)

#define BGSTORE(REG) do { \
    _Pragma("unroll") for (int _j = 0; _j < 4; ++_j) \
      *(us8*)(smem + 65536u + (REG) * 32768u + btile * 8192u + \
              (((brow << 7) + (bkb + (_j << 4))) ^ ((brow & 7) << 4))) \
          = cvt8(pb[2 * _j], pb[2 * _j + 1]); } while (0)

#define COMP(ABUF, BREG, KTL) do { \
    const unsigned char* Ab = smem + (ABUF) * 32768u; \
    const unsigned char* Bb = smem + 65536u + (BREG) * 32768u + (KTL) * 8192u; \
    const int fr = lane & 15, k16 = (lane >> 4) << 4; \
    _Pragma("unroll") for (int kk = 0; kk < 2; ++kk) { \
      short8 a[4], fi, fg; \
      _Pragma("unroll") for (int i = 0; i < 4; ++i) { \
        const int rw = (wm << 6) + (i << 4) + fr; \
        a[i] = *(const short8*)(Ab + (((rw << 7) + (kk << 6) + k16) ^ ((rw & 7) << 4))); \
      } \
      { const int rw = (wh << 4) + fr; \
        fi = *(const short8*)(Bb + (((rw << 7) + (kk << 6) + k16) ^ ((rw & 7) << 4))); \
        fg = *(const short8*)(Bb + ((((rw + 32) << 7) + (kk << 6) + k16) ^ ((rw & 7) << 4))); } \
      _Pragma("unroll") for (int i = 0; i < 4; ++i) { \
        acc_i[i] = __builtin_amdgcn_mfma_f32_16x16x32_bf16(a[i], fi, acc_i[i], 0, 0, 0); \
        acc_g[i] = __builtin_amdgcn_mfma_f32_16x16x32_bf16(a[i], fg, acc_g[i], 0, 0, 0); } \
    } } while (0)

  // prologue: group 0 + A tile 0
  BGLOAD(0);
  ALOAD(0);
  WAITVM0();
  BGSTORE(0);
  ASTORE(0);
  sync_ds();

#pragma unroll
  for (int kt = 0; kt < 16; ++kt) {
    if (kt < 15) ALOAD(kt + 1);
    COMP(kt & 1, (kt >> 2) & 1, kt & 3);
    WAITVM0();
    if (kt < 15) ASTORE((kt + 1) & 1);
    if ((kt & 3) == 3 && kt < 15) BGSTORE(((kt >> 2) + 1) & 1);
    if ((kt & 3) == 0 && kt < 12) BGLOAD((kt >> 2) + 1);
    sync_ds();
  }

  // epilogue: c = sigmoid(i+bi)*tanh(g+bg)*imp -> aggT (swizzled tile layout)
  const int col16 = lane & 15, row4 = (lane >> 4) << 2;
  const float impv = imp[v];
  const int h = h0 + (wh << 4) + col16;
  const float bsi = b_ih[v * 2048 + h] + b_hh[v * 2048 + h];
  const float bsg = b_ih[v * 2048 + 1024 + h] + b_hh[v * 2048 + 1024 + h];
  char* obase = (char*)aggT + ((size_t)v * 8 + (h >> 6)) * 32768;
  const int hc = h & 63;
#pragma unroll
  for (int i = 0; i < 4; ++i)
#pragma unroll
    for (int r = 0; r < 4; ++r) {
      const int m = (wm << 6) + (i << 4) + row4 + r;
      const float ii = acc_i[i][r] + bsi;
      const float gg = acc_g[i][r] + bsg;
      const float c = (1.0f / (1.0f + __expf(-ii))) * tanhf(gg) * impv;
      *(unsigned short*)(obase + (((m << 7) + (hc << 1)) ^ ((m & 7) << 4))) = f2bf(c);
    }
#undef COMP
#undef ALOAD
#undef ASTORE
#undef BGLOAD
#undef BGSTORE
}

// ---------------------------------------------------------------------------
// K3: mlp1 split-K GEMM, same page-burst structure.
//   Block (split s, n-tile 32), grid 512. B slice = 32 rows x 4 KB contiguous;
//   supergroups of 4 k-tiles (1 KB/row). A: aggT via gload_lds dbuf (L2).
// ---------------------------------------------------------------------------
__global__ __launch_bounds__(512, 2) void k3_mlp1(
    const unsigned short* __restrict__ aggT,
    const float* __restrict__ Wm,          // [1024][16384]
    unsigned short* __restrict__ part)     // [16][256][1024] bf16
{
  const int bid = blockIdx.x;
  const int chunk = ((bid & 7) << 6) | (bid >> 3);
  const int s = chunk >> 5;                 // 0..15
  const int n0 = (chunk & 31) << 5;         // 0..992

  const int t = threadIdx.x, lane = t & 63, wave = t >> 6;
  const int wm = wave & 3, wn = wave >> 2;  // wn 0..1

  __shared__ __align__(16) unsigned char smem[98304]; // A:2x32K @0, B:2x16K @65536

  const char* Asrc = (const char*)aggT + (size_t)s * 16 * 32768 + wave * 1024 + lane * 16;
  const unsigned aoff = wave * 1024u;

  // B: 32 rows; thread reads 64 B contiguous (16 floats) per supergroup
  const int brow = t >> 4;                  // 0..31
  const float* Bsrc = Wm + (size_t)(n0 + brow) * 16384 + (size_t)s * 1024 + ((t & 15) << 4);
  const unsigned btile = (unsigned)((t & 15) >> 2);
  const unsigned bkb   = (unsigned)(((t & 15) & 3) << 5);

  f32x4 acc[4] = {};
  f32x4 pb[4];

#define GLA(BUF, KT) do { \
    _Pragma("unroll") for (int _r = 0; _r < 4; ++_r) \
      gload16(Asrc + (KT) * 32768 + _r * 8192, \
              smem + (BUF) * 32768u + aoff + _r * 8192); } while (0)

#define BGLOAD(G) do { \
    _Pragma("unroll") for (int _e = 0; _e < 4; ++_e) \
      pb[_e] = gldx4(Bsrc + (size_t)(G) * 256 + _e * 4); } while (0)

#define BGSTORE(REG) do { \
    _Pragma("unroll") for (int _j = 0; _j < 2; ++_j) \
      *(us8*)(smem + 65536u + (REG) * 16384u + btile * 4096u + \
              (((brow << 7) + (bkb + (_j << 4))) ^ ((brow & 7) << 4))) \
          = cvt8(pb[2 * _j], pb[2 * _j + 1]); } while (0)

#define COMP(ABUF, BREG, KTL) do { \
    const unsigned char* Ab = smem + (ABUF) * 32768u; \
    const unsigned char* Bb = smem + 65536u + (BREG) * 16384u + (KTL) * 4096u; \
    const int fr = lane & 15, k16 = (lane >> 4) << 4; \
    _Pragma("unroll") for (int kk = 0; kk < 2; ++kk) { \
      short8 a[4], bfr; \
      _Pragma("unroll") for (int i = 0; i < 4; ++i) { \
        const int rw = (wm << 6) + (i << 4) + fr; \
        a[i] = *(const short8*)(Ab + (((rw << 7) + (kk << 6) + k16) ^ ((rw & 7) << 4))); \
      } \
      { const int rw = (wn << 4) + fr; \
        bfr = *(const short8*)(Bb + (((rw << 7) + (kk << 6) + k16) ^ ((rw & 7) << 4))); } \
      _Pragma("unroll") for (int i = 0; i < 4; ++i) \
        acc[i] = __builtin_amdgcn_mfma_f32_16x16x32_bf16(a[i], bfr, acc[i], 0, 0, 0); \
    } } while (0)

  // prologue
  BGLOAD(0);
  GLA(0, 0);
  WAITVM0();
  BGSTORE(0);
  sync_ds();

#pragma unroll
  for (int kt = 0; kt < 16; ++kt) {
    if (kt < 15) GLA((kt + 1) & 1, kt + 1);
    COMP(kt & 1, (kt >> 2) & 1, kt & 3);
    WAITVM0();
    if ((kt & 3) == 3 && kt < 15) BGSTORE(((kt >> 2) + 1) & 1);
    if ((kt & 3) == 0 && kt < 12) BGLOAD((kt >> 2) + 1);
    sync_ds();
  }

  const int col16 = lane & 15, row4 = (lane >> 4) << 2;
  unsigned short* outp = part + (size_t)s * BATCH * 1024;
#pragma unroll
  for (int i = 0; i < 4; ++i)
#pragma unroll
    for (int r = 0; r < 4; ++r)
      outp[(size_t)((wm << 6) + (i << 4) + row4 + r) * 1024
           + n0 + (wn << 4) + col16] = f2bf(acc[i][r]);
#undef COMP
#undef GLA
#undef BGLOAD
#undef BGSTORE
}

// ---------------------------------------------------------------------------
// K4: fused head (bf16 partials). One block per batch row, 512 threads.
// ---------------------------------------------------------------------------
__global__ __launch_bounds__(512) void k4_head(
    const unsigned short* __restrict__ part,   // [16][256][1024] bf16
    const float* __restrict__ b1,
    const float* __restrict__ w2,
    const float* __restrict__ b2,
    float* __restrict__ out)
{
  const int b = blockIdx.x;
  const int t = threadIdx.x;          // 0..511
  const int n0 = t << 1;
  float s0 = b1[n0], s1 = b1[n0 + 1];
#pragma unroll
  for (int sp = 0; sp < SPLIT; ++sp) {
    const unsigned u = *(const unsigned*)(part + ((size_t)sp * BATCH + b) * 1024 + n0);
    union { unsigned u; float f; } lo, hi;
    lo.u = u << 16;
    hi.u = u & 0xffff0000u;
    s0 += lo.f;
    s1 += hi.f;
  }
  float accum = fmaxf(s0, 0.0f) * w2[n0] + fmaxf(s1, 0.0f) * w2[n0 + 1];
  __shared__ float red[8];
#pragma unroll
  for (int off = 32; off > 0; off >>= 1)
    accum += __shfl_down(accum, off);
  if ((t & 63) == 0) red[t >> 6] = accum;
  __syncthreads();
  if (t == 0) {
    float r = b2[0];
#pragma unroll
    for (int w = 0; w < 8; ++w) r += red[w];
    out[b] = r;
  }
}

// ---------------------------------------------------------------------------
extern "C" void kernel_launch(void* const* d_in, const int* in_sizes, int n_in,
                              void* d_out, int out_size, void* d_ws, size_t ws_size,
                              hipStream_t stream) {
  const float* inputs = (const float*)d_in[0];
  const float* W_ih   = (const float*)d_in[1];
  // d_in[2] = W_hh: unused (h0 == 0)
  const float* b_ih   = (const float*)d_in[3];
  const float* b_hh   = (const float*)d_in[4];
  const float* imp    = (const float*)d_in[5];
  const float* m1w    = (const float*)d_in[6];
  const float* m1b    = (const float*)d_in[7];
  const float* m2w    = (const float*)d_in[8];
  const float* m2b    = (const float*)d_in[9];
  float* out = (float*)d_out;

  char* ws = (char*)d_ws;
  unsigned short* aggT = (unsigned short*)ws;                // 8 MB tiled bf16
  unsigned short* part = (unsigned short*)(ws + (8u << 20)); // 8 MB bf16

  k1_gates<<<dim3(512), 512, 0, stream>>>(inputs, W_ih, b_ih, b_hh, imp, aggT);
  k3_mlp1 <<<dim3(512), 512, 0, stream>>>(aggT, m1w, part);
  k4_head <<<dim3(256), 512, 0, stream>>>(part, m1b, m2w, m2b, out);
}